// Round 2
// baseline (607.328 us; speedup 1.0000x reference)
//
#include <hip/hip_runtime.h>

#define N_SEQ 512
#define N_RES 384
#define C_M   256

typedef __bf16 bf16;
typedef __bf16 bf16x4 __attribute__((ext_vector_type(4)));
typedef __bf16 bf16x8 __attribute__((ext_vector_type(8)));
typedef float  f32x4  __attribute__((ext_vector_type(4)));
typedef float  f32x16 __attribute__((ext_vector_type(16)));

static __device__ __forceinline__ bf16x8 ld8(const bf16* p) {
  bf16x4 lo = *(const bf16x4*)p;
  bf16x4 hi = *(const bf16x4*)(p + 4);
  bf16x8 r;
  r[0] = lo[0]; r[1] = lo[1]; r[2] = lo[2]; r[3] = lo[3];
  r[4] = hi[0]; r[5] = hi[1]; r[6] = hi[2]; r[7] = hi[3];
  return r;
}

// s_waitcnt vmcnt(N) only (lgkmcnt/expcnt = no-wait)
template <int N> __device__ __forceinline__ void wait_vm() {
  __builtin_amdgcn_s_waitcnt((N & 15) | ((N >> 4) << 14) | (7 << 4) | (15 << 8));
}

// Workspace layout (bytes):
//   leftT  [12288][512] bf16 @ 0          (m=b*32+c, k=a)
//   rightT [12288][512] bf16 @ 12582912   (n=d*32+e, k=a)
//   WtEp   [128][1024]  bf16 @ 25165824   (f, k=e*32+c)  e-major!
//   projW2 [64][256]    bf16 @ 25427968   (o, m)  = g[m]*w[m][o]
//   Svec   [64] f32     @ 25460736        column sums of projW2
//   bias2  [64] f32     @ 25460992        bias + o@w
//   recip  [384*384] f32 @ 25461248

// ---------------- aux: norm + weight prep, one launch ----------------
__global__ void aux_kernel(const float* __restrict__ mask,
                           const float* __restrict__ lw, const float* __restrict__ rw,
                           const float* __restrict__ ow,
                           const float* __restrict__ ln_scale, const float* __restrict__ ln_offset,
                           const float* __restrict__ left_b, const float* __restrict__ right_b,
                           bf16* __restrict__ projW2, bf16* __restrict__ WtEp,
                           float* __restrict__ Svec, float* __restrict__ bias2,
                           float* __restrict__ recip) {
  int blk = blockIdx.x, t = threadIdx.x;
  if (blk < 576) {
    int bx = blk % 24, by = blk / 24;
    int b = bx * 16 + (t & 15), d = by * 16 + (t >> 4);
    float s = 0.f;
#pragma unroll 8
    for (int a = 0; a < N_SEQ; ++a)
      s += mask[a * N_RES + b] * mask[a * N_RES + d];
    recip[b * N_RES + d] = 1.0f / (1e-3f + s);
  } else if (blk < 1088) {
    int i2 = (blk - 576) * 256 + t;          // [0, 131072)
    int f = i2 >> 10, k = i2 & 1023, e = k >> 5, c = k & 31;
    WtEp[i2] = (bf16)ow[(c * 32 + e) * 128 + f];   // WtEp[f][e*32+c]
  } else if (blk < 1152) {
    int idx = (blk - 1088) * 256 + t;        // [0, 16384)
    int o = idx >> 8, m = idx & 255;
    float w = (o < 32) ? lw[m * 32 + o] : rw[m * 32 + (o - 32)];
    projW2[idx] = (bf16)(ln_scale[m] * w);
  } else {
    if (t < 64) {
      int o = t;
      float s = 0.f, b2 = (o < 32) ? left_b[o] : right_b[o - 32];
      for (int m = 0; m < 256; ++m) {
        float w = (o < 32) ? lw[m * 32 + o] : rw[m * 32 + (o - 32)];
        s += (float)(bf16)(ln_scale[m] * w);   // match MFMA's bf16 W' exactly
        b2 += ln_offset[m] * w;
      }
      Svec[o] = s; bias2[o] = b2;
    }
  }
}

// ---------------- LN + projection: stats via LDS pass, mean-correction post-GEMM ----------------
// block: 128 a-rows, fixed b. grid (4, 384).
__launch_bounds__(256)
__global__ void ln_project_kernel(const float* __restrict__ act, const float* __restrict__ mask,
                                  const bf16* __restrict__ projW2,
                                  const float* __restrict__ Svec, const float* __restrict__ bias2,
                                  bf16* __restrict__ leftT, bf16* __restrict__ rightT) {
  __shared__ __align__(16) bf16 At[128 * 264];   // raw bf16 x, [128][256+8]
  __shared__ float2 muRow[128];
  bf16* outbuf = At;                             // aliased after GEMM: [64 o][136 a]

  const int t = threadIdx.x;
  const int b = blockIdx.y;
  const int a0 = blockIdx.x * 128;
  const int wv = t >> 6, lane = t & 63;
  const int q = lane >> 4, l15 = lane & 15;

  // ---- A: coalesced 1KB row loads, store raw bf16 ----
#pragma unroll 4
  for (int it = 0; it < 32; ++it) {
    const int row = it * 4 + wv;
    float4 v = *(const float4*)(act + ((size_t)(a0 + row) * N_RES + b) * C_M + lane * 4);
    bf16x4 r;
    r[0] = (bf16)v.x; r[1] = (bf16)v.y; r[2] = (bf16)v.z; r[3] = (bf16)v.w;
    *(bf16x4*)&At[row * 264 + lane * 4] = r;
  }
  __syncthreads();

  // ---- A2: per-half-row stats from LDS (no butterfly storm) ----
  {
    int row = t >> 1, half = t & 1;
    const bf16* base = At + row * 264 + half * 128;
    float s1 = 0.f, s2 = 0.f;
#pragma unroll
    for (int i = 0; i < 16; ++i) {
      int ch = ((i + row) & 15) * 8;             // rotation breaks bank collisions
      bf16x8 v = *(const bf16x8*)(base + ch);
#pragma unroll
      for (int u = 0; u < 8; ++u) { float x = (float)v[u]; s1 += x; s2 += x * x; }
    }
    s1 += __shfl_xor(s1, 1);
    s2 += __shfl_xor(s2, 1);
    if (half == 0) {
      float mean = s1 * (1.f / 256.f);
      float var  = s2 * (1.f / 256.f) - mean * mean;
      muRow[row] = make_float2(mean, rsqrtf(var + 1e-5f));
    }
  }

  // ---- B: GEMM raw x @ W'  (M=128, N=64, K=256) ----
  f32x4 acc[2][4] = {};
#pragma unroll
  for (int s = 0; s < 8; ++s) {
    bf16x8 af[2], bfr[4];
#pragma unroll
    for (int i = 0; i < 2; ++i)
      af[i] = *(bf16x8*)&At[(wv * 32 + i * 16 + l15) * 264 + s * 32 + q * 8];
#pragma unroll
    for (int j = 0; j < 4; ++j)
      bfr[j] = *(const bf16x8*)&projW2[(j * 16 + l15) * 256 + s * 32 + q * 8];
#pragma unroll
    for (int i = 0; i < 2; ++i)
#pragma unroll
      for (int j = 0; j < 4; ++j)
        acc[i][j] = __builtin_amdgcn_mfma_f32_16x16x32_bf16(af[i], bfr[j], acc[i][j], 0, 0, 0);
  }
  __syncthreads();

  // ---- C: z = rstd*(P - mu*S) + bias2, then *mask ----
  float Sv[4], Bv[4];
#pragma unroll
  for (int j = 0; j < 4; ++j) { Sv[j] = Svec[j * 16 + l15]; Bv[j] = bias2[j * 16 + l15]; }
#pragma unroll
  for (int i = 0; i < 2; ++i) {
#pragma unroll
    for (int r = 0; r < 4; ++r) {
      int a_local = wv * 32 + i * 16 + q * 4 + r;
      float2 ms = muRow[a_local];
      float mv = mask[(size_t)(a0 + a_local) * N_RES + b];
#pragma unroll
      for (int j = 0; j < 4; ++j) {
        float val = (ms.y * (acc[i][j][r] - ms.x * Sv[j]) + Bv[j]) * mv;
        outbuf[(j * 16 + l15) * 136 + a_local] = (bf16)val;
      }
    }
  }
  __syncthreads();

  // ---- D: coalesced write to leftT/rightT ----
  {
    int o = t >> 2, part = t & 3;
    bf16* dst = (o < 32) ? (leftT + (size_t)(b * 32 + o) * 512)
                         : (rightT + (size_t)(b * 32 + (o - 32)) * 512);
#pragma unroll
    for (int v = 0; v < 4; ++v) {
      int asub = part * 32 + v * 8;
      bf16x8 val = *(bf16x8*)&outbuf[o * 136 + asub];
      *(bf16x8*)(dst + a0 + asub) = val;
    }
  }
}

// ---------------- main kernel: 256x256 tile, merged-phase pipeline ----------------
// 16 phases (2 per BK=64 K-tile), m201 shape: per phase {issue 2 stage units; 12 ds_reads;
// counted vmcnt(8); barrier; lgkmcnt(0); setprio; 16 MFMA; setprio; barrier}.
// A and B staged via global_load_lds into 4 rotating 16KB LDS blocks per matrix
// ([dbuf parity][k-half], [256 rows][32 k], XOR swizzle on the GLOBAL source so the LDS
// dest stays linear). Stage units issued 3 phases before first consumption; vmcnt never
// drains mid-loop (8 steady, 8/4/0 tail).
__launch_bounds__(512, 2)
__global__ void outer_kernel(const bf16* __restrict__ leftT, const bf16* __restrict__ rightT,
                             const bf16* __restrict__ WtEp, const float* __restrict__ output_b,
                             const float* __restrict__ recip, float* __restrict__ out) {
  __shared__ __align__(16) union {
    bf16 AB[8 * 8192];       // 131072 B : [dbuf][A|B][khalf][256*32] swizzled bf16
    bf16 Aep[64 * 1156];     // 147968 B : inter tile, [pair][e*36 + c]
    float P[4 * 64 * 2 * 64];// 131072 B : epilogue partials [kq][pair][fh][fl]
  } sm;

  const int t_ = threadIdx.x;
  const int sq = blockIdx.x >> 4, wi = blockIdx.x & 15;
  const int m0 = ((sq % 12) * 4 + (wi & 3)) * 256;
  const int n0 = ((sq / 12) * 4 + (wi >> 2)) * 256;

  const int wv = t_ >> 6, lane = t_ & 63;
  const int q = lane >> 4, l15 = lane & 15;
  const int l31 = lane & 31, h = lane >> 5;
  const int wm = (wv & 1) * 128, wn = (wv >> 1) * 64;

  // staging constants: wave writes 2x1KB linear LDS; source k-chunk pre-swizzled so a
  // read of LDS[row][kc ^ ((row>>1)&3)] returns logical [row][kc]
  const int stR  = wv * 32 + (lane >> 2);                  // row, + _j*16
  const int stKC = ((lane & 3) ^ ((lane >> 3) & 3)) * 8;   // source k-chunk (elems)
  const int rsw  = (l31 >> 1) & 3;                         // read-side XOR term

  const bf16* gA = leftT  + (size_t)m0 * 512;
  const bf16* gB = rightT + (size_t)n0 * 512;

#define BLK(d, mat, hf) ((((d) * 2 + (mat)) * 2 + (hf)) * 8192)
#define STAGE(mat, T, hf) do {                                                              \
    const bf16* _g = (mat) ? gB : gA;                                                       \
    bf16* _l = sm.AB + BLK((T) & 1, mat, hf);                                               \
    _Pragma("unroll")                                                                       \
    for (int _j = 0; _j < 2; ++_j) {                                                        \
      const bf16* _s = _g + (size_t)(stR + _j * 16) * 512 + (T) * 64 + (hf) * 32 + stKC;    \
      __builtin_amdgcn_global_load_lds(                                                     \
          (const __attribute__((address_space(1))) void*)_s,                                \
          (__attribute__((address_space(3))) void*)(_l + (wv * 2 + _j) * 512), 16, 0, 0);   \
    }                                                                                       \
  } while (0)

  f32x16 acc[4][2] = {};

  // prologue: khalf(0,0), khalf(0,1), khalf(1,0) for both matrices (12 vmem instrs/wave);
  // counted wait: khalf(0,0) landed, the rest may stay in flight
  STAGE(0, 0, 0); STAGE(1, 0, 0);
  STAGE(0, 0, 1); STAGE(1, 0, 1);
  STAGE(0, 1, 0); STAGE(1, 1, 0);
  wait_vm<8>();
  __builtin_amdgcn_s_barrier();

#pragma unroll
  for (int t = 0; t < 8; ++t) {
#pragma unroll
    for (int hf = 0; hf < 2; ++hf) {
      // issue the stage units freeing this phase's parity slot 3 phases out:
      // P(t,0) stages (t+1,1)  [overwrites blocks last read at P(t-1,1)];
      // P(t,1) stages (t+2,0)  [overwrites blocks last read at P(t,0)].
      if (hf == 0) { if (t < 7) { STAGE(0, t + 1, 1); STAGE(1, t + 1, 1); } }
      else         { if (t < 6) { STAGE(0, t + 2, 0); STAGE(1, t + 2, 0); } }

      // register fragments for both k16-steps of this khalf (resident: guarded by the
      // previous phase's counted vmcnt + barrier)
      const bf16* Ab = sm.AB + BLK(t & 1, 0, hf);
      const bf16* Bb = sm.AB + BLK(t & 1, 1, hf);
      bf16x8 af[2][4], b0[2], b1[2];
#pragma unroll
      for (int ss = 0; ss < 2; ++ss) {
        const int coff = ((ss * 2 + h) ^ rsw) * 8;
#pragma unroll
        for (int i = 0; i < 4; ++i)
          af[ss][i] = *(const bf16x8*)&Ab[(wm + i * 32 + l31) * 32 + coff];
        b0[ss] = *(const bf16x8*)&Bb[(wn + l31) * 32 + coff];
        b1[ss] = *(const bf16x8*)&Bb[(wn + 32 + l31) * 32 + coff];
      }

      // counted vmcnt guarding the NEXT phase's blocks (4 instrs/unit-pair):
      // steady state 8 in flight; tail tightens 8 -> 4 -> 0.
      if (hf == 0) { if (t < 7) wait_vm<8>(); else wait_vm<0>(); }
      else         { if (t < 6) wait_vm<8>(); else if (t == 6) wait_vm<4>(); }

      __builtin_amdgcn_s_barrier();
      asm volatile("s_waitcnt lgkmcnt(0)" ::: "memory");
      __builtin_amdgcn_sched_barrier(0);
      __builtin_amdgcn_s_setprio(1);
#pragma unroll
      for (int ss = 0; ss < 2; ++ss)
#pragma unroll
        for (int i = 0; i < 4; ++i) {
          acc[i][0] = __builtin_amdgcn_mfma_f32_32x32x16_bf16(af[ss][i], b0[ss], acc[i][0], 0, 0, 0);
          acc[i][1] = __builtin_amdgcn_mfma_f32_32x32x16_bf16(af[ss][i], b1[ss], acc[i][1], 0, 0, 0);
        }
      __builtin_amdgcn_s_setprio(0);
      __builtin_amdgcn_s_barrier();   // readers done before next phase's stage overwrites
    }
  }
  __syncthreads();   // full drain before LDS union is repurposed (outstanding vmem = 0 here)

  // scatter inter tile -> Aep[pair][e*36 + c], b64-packed (4 consecutive c per reg-group)
#pragma unroll
  for (int i = 0; i < 4; ++i) {
#pragma unroll
    for (int j = 0; j < 2; ++j) {
      int pair = ((wv & 1) * 4 + i) * 8 + (wv >> 1) * 2 + j;
      int base = pair * 1156 + l31 * 36;   // e = l31
#pragma unroll
      for (int g = 0; g < 4; ++g) {
        bf16x4 v;
        v[0] = (bf16)acc[i][j][4 * g + 0];
        v[1] = (bf16)acc[i][j][4 * g + 1];
        v[2] = (bf16)acc[i][j][4 * g + 2];
        v[3] = (bf16)acc[i][j][4 * g + 3];
        *(bf16x4*)&sm.Aep[base + 8 * g + 4 * h] = v;   // c = 8g+4h+{0..3}
      }
    }
  }
  __syncthreads();

  // epilogue: each wave: k-slice 256 (kq), f-slice 64 (fh), all 64 pairs. W read once/block.
  const int kq = wv & 3, fh = wv >> 2;
  f32x4 eacc[4][4] = {};   // [mt][j]
#pragma unroll
  for (int si = 0; si < 8; ++si) {
    int e = kq * 8 + si;
    bf16x8 wf[4];
#pragma unroll
    for (int j = 0; j < 4; ++j)
      wf[j] = *(const bf16x8*)&WtEp[(size_t)(fh * 64 + j * 16 + l15) * 1024 + e * 32 + q * 8];
    bf16x8 af[4];
#pragma unroll
    for (int mt = 0; mt < 4; ++mt)
      af[mt] = ld8(&sm.Aep[(mt * 16 + l15) * 1156 + e * 36 + q * 8]);
#pragma unroll
    for (int mt = 0; mt < 4; ++mt)
#pragma unroll
      for (int j = 0; j < 4; ++j)
        eacc[mt][j] = __builtin_amdgcn_mfma_f32_16x16x32_bf16(af[mt], wf[j], eacc[mt][j], 0, 0, 0);
  }
  __syncthreads();

  // write partials P[kq][pair][fh][fl]
#pragma unroll
  for (int mt = 0; mt < 4; ++mt)
#pragma unroll
    for (int j = 0; j < 4; ++j)
#pragma unroll
      for (int r = 0; r < 4; ++r) {
        int pair = mt * 16 + q * 4 + r;
        int fl = j * 16 + l15;
        sm.P[((kq * 64 + pair) * 2 + fh) * 64 + fl] = eacc[mt][j][r];
      }
  __syncthreads();

  // reduce over kq, add bias, scale by recip, write out
#pragma unroll
  for (int gg = 0; gg < 4; ++gg) {
    int g = t_ + 512 * gg;          // [0, 2048)
    int pair = g >> 5, f4 = g & 31;
    int f = f4 * 4, fh2 = f >> 6, fl = f & 63;
    f32x4 s = {};
#pragma unroll
    for (int k2 = 0; k2 < 4; ++k2)
      s += *(f32x4*)&sm.P[((k2 * 64 + pair) * 2 + fh2) * 64 + fl];
    int b = (m0 >> 5) + (pair >> 3);
    int d = (n0 >> 5) + (pair & 7);
    float rc = recip[b * N_RES + d];
    float4 ob = *(const float4*)(output_b + f);
    f32x4 o;
    o[0] = (s[0] + ob.x) * rc; o[1] = (s[1] + ob.y) * rc;
    o[2] = (s[2] + ob.z) * rc; o[3] = (s[3] + ob.w) * rc;
    *(f32x4*)(out + ((size_t)b * N_RES + d) * 128 + f) = o;
  }
}

extern "C" void kernel_launch(void* const* d_in, const int* in_sizes, int n_in,
                              void* d_out, int out_size, void* d_ws, size_t ws_size,
                              hipStream_t stream) {
  const float* act       = (const float*)d_in[0];
  const float* mask      = (const float*)d_in[1];
  const float* ln_scale  = (const float*)d_in[2];
  const float* ln_offset = (const float*)d_in[3];
  const float* left_w    = (const float*)d_in[4];
  const float* left_b    = (const float*)d_in[5];
  const float* right_w   = (const float*)d_in[6];
  const float* right_b   = (const float*)d_in[7];
  const float* output_w  = (const float*)d_in[8];
  const float* output_b  = (const float*)d_in[9];
  float* out = (float*)d_out;

  char* ws = (char*)d_ws;
  bf16* leftT   = (bf16*)(ws);
  bf16* rightT  = (bf16*)(ws + 12582912);
  bf16* WtEp    = (bf16*)(ws + 25165824);
  bf16* projW2  = (bf16*)(ws + 25427968);
  float* Svec   = (float*)(ws + 25460736);
  float* bias2  = (float*)(ws + 25460992);
  float* recip  = (float*)(ws + 25461248);

  hipLaunchKernelGGL(aux_kernel, dim3(1153), dim3(256), 0, stream,
                     mask, left_w, right_w, output_w, ln_scale, ln_offset,
                     left_b, right_b, projW2, WtEp, Svec, bias2, recip);
  hipLaunchKernelGGL(ln_project_kernel, dim3(4, 384), dim3(256), 0, stream,
                     act, mask, projW2, Svec, bias2, leftT, rightT);
  hipLaunchKernelGGL(outer_kernel, dim3(2304), dim3(512), 0, stream,
                     leftT, rightT, WtEp, output_b, recip, out);
}

// Round 3
// 578.780 us; speedup vs baseline: 1.0493x; 1.0493x over previous
//
#include <hip/hip_runtime.h>

#define N_SEQ 512
#define N_RES 384
#define C_M   256

typedef __bf16 bf16;
typedef __bf16 bf16x4 __attribute__((ext_vector_type(4)));
typedef __bf16 bf16x8 __attribute__((ext_vector_type(8)));
typedef float  f32x4  __attribute__((ext_vector_type(4)));
typedef float  f32x16 __attribute__((ext_vector_type(16)));

static __device__ __forceinline__ bf16x8 ld8(const bf16* p) {
  bf16x4 lo = *(const bf16x4*)p;
  bf16x4 hi = *(const bf16x4*)(p + 4);
  bf16x8 r;
  r[0] = lo[0]; r[1] = lo[1]; r[2] = lo[2]; r[3] = lo[3];
  r[4] = hi[0]; r[5] = hi[1]; r[6] = hi[2]; r[7] = hi[3];
  return r;
}

// s_waitcnt vmcnt(N) only (lgkmcnt/expcnt = no-wait)
template <int N> __device__ __forceinline__ void wait_vm() {
  __builtin_amdgcn_s_waitcnt((N & 15) | ((N >> 4) << 14) | (7 << 4) | (15 << 8));
}

// Workspace layout (bytes):
//   leftT  [12288][512] bf16 @ 0          (m=b*32+c, k=a)
//   rightT [12288][512] bf16 @ 12582912   (n=d*32+e, k=a)
//   WtEp   [128][1024]  bf16 @ 25165824   (f, k=e*32+c)  e-major!
//   projW2 [64][256]    bf16 @ 25427968   (o, m)  = g[m]*w[m][o]
//   Svec   [64] f32     @ 25460736        column sums of projW2
//   bias2  [64] f32     @ 25460992        bias + o@w
//   recip  [384*384] f32 @ 25461248

// ---------------- aux: norm + weight prep, one launch ----------------
__global__ void aux_kernel(const float* __restrict__ mask,
                           const float* __restrict__ lw, const float* __restrict__ rw,
                           const float* __restrict__ ow,
                           const float* __restrict__ ln_scale, const float* __restrict__ ln_offset,
                           const float* __restrict__ left_b, const float* __restrict__ right_b,
                           bf16* __restrict__ projW2, bf16* __restrict__ WtEp,
                           float* __restrict__ Svec, float* __restrict__ bias2,
                           float* __restrict__ recip) {
  int blk = blockIdx.x, t = threadIdx.x;
  if (blk < 576) {
    int bx = blk % 24, by = blk / 24;
    int b = bx * 16 + (t & 15), d = by * 16 + (t >> 4);
    float s = 0.f;
#pragma unroll 8
    for (int a = 0; a < N_SEQ; ++a)
      s += mask[a * N_RES + b] * mask[a * N_RES + d];
    recip[b * N_RES + d] = 1.0f / (1e-3f + s);
  } else if (blk < 1088) {
    int i2 = (blk - 576) * 256 + t;          // [0, 131072)
    int f = i2 >> 10, k = i2 & 1023, e = k >> 5, c = k & 31;
    WtEp[i2] = (bf16)ow[(c * 32 + e) * 128 + f];   // WtEp[f][e*32+c]
  } else if (blk < 1152) {
    int idx = (blk - 1088) * 256 + t;        // [0, 16384)
    int o = idx >> 8, m = idx & 255;
    float w = (o < 32) ? lw[m * 32 + o] : rw[m * 32 + (o - 32)];
    projW2[idx] = (bf16)(ln_scale[m] * w);
  } else {
    if (t < 64) {
      int o = t;
      float s = 0.f, b2 = (o < 32) ? left_b[o] : right_b[o - 32];
      for (int m = 0; m < 256; ++m) {
        float w = (o < 32) ? lw[m * 32 + o] : rw[m * 32 + (o - 32)];
        s += (float)(bf16)(ln_scale[m] * w);   // match MFMA's bf16 W' exactly
        b2 += ln_offset[m] * w;
      }
      Svec[o] = s; bias2[o] = b2;
    }
  }
}

// ---------------- LN + projection: stats via LDS pass, mean-correction post-GEMM ----------------
// block: 128 a-rows, fixed b. grid (4, 384).
__launch_bounds__(256)
__global__ void ln_project_kernel(const float* __restrict__ act, const float* __restrict__ mask,
                                  const bf16* __restrict__ projW2,
                                  const float* __restrict__ Svec, const float* __restrict__ bias2,
                                  bf16* __restrict__ leftT, bf16* __restrict__ rightT) {
  __shared__ __align__(16) bf16 At[128 * 264];   // raw bf16 x, [128][256+8]
  __shared__ float2 muRow[128];
  bf16* outbuf = At;                             // aliased after GEMM: [64 o][136 a]

  const int t = threadIdx.x;
  const int b = blockIdx.y;
  const int a0 = blockIdx.x * 128;
  const int wv = t >> 6, lane = t & 63;
  const int q = lane >> 4, l15 = lane & 15;

  // ---- A: coalesced 1KB row loads, store raw bf16 ----
#pragma unroll 4
  for (int it = 0; it < 32; ++it) {
    const int row = it * 4 + wv;
    float4 v = *(const float4*)(act + ((size_t)(a0 + row) * N_RES + b) * C_M + lane * 4);
    bf16x4 r;
    r[0] = (bf16)v.x; r[1] = (bf16)v.y; r[2] = (bf16)v.z; r[3] = (bf16)v.w;
    *(bf16x4*)&At[row * 264 + lane * 4] = r;
  }
  __syncthreads();

  // ---- A2: per-half-row stats from LDS (no butterfly storm) ----
  {
    int row = t >> 1, half = t & 1;
    const bf16* base = At + row * 264 + half * 128;
    float s1 = 0.f, s2 = 0.f;
#pragma unroll
    for (int i = 0; i < 16; ++i) {
      int ch = ((i + row) & 15) * 8;             // rotation breaks bank collisions
      bf16x8 v = *(const bf16x8*)(base + ch);
#pragma unroll
      for (int u = 0; u < 8; ++u) { float x = (float)v[u]; s1 += x; s2 += x * x; }
    }
    s1 += __shfl_xor(s1, 1);
    s2 += __shfl_xor(s2, 1);
    if (half == 0) {
      float mean = s1 * (1.f / 256.f);
      float var  = s2 * (1.f / 256.f) - mean * mean;
      muRow[row] = make_float2(mean, rsqrtf(var + 1e-5f));
    }
  }

  // ---- B: GEMM raw x @ W'  (M=128, N=64, K=256) ----
  f32x4 acc[2][4] = {};
#pragma unroll
  for (int s = 0; s < 8; ++s) {
    bf16x8 af[2], bfr[4];
#pragma unroll
    for (int i = 0; i < 2; ++i)
      af[i] = *(bf16x8*)&At[(wv * 32 + i * 16 + l15) * 264 + s * 32 + q * 8];
#pragma unroll
    for (int j = 0; j < 4; ++j)
      bfr[j] = *(const bf16x8*)&projW2[(j * 16 + l15) * 256 + s * 32 + q * 8];
#pragma unroll
    for (int i = 0; i < 2; ++i)
#pragma unroll
      for (int j = 0; j < 4; ++j)
        acc[i][j] = __builtin_amdgcn_mfma_f32_16x16x32_bf16(af[i], bfr[j], acc[i][j], 0, 0, 0);
  }
  __syncthreads();

  // ---- C: z = rstd*(P - mu*S) + bias2, then *mask ----
  float Sv[4], Bv[4];
#pragma unroll
  for (int j = 0; j < 4; ++j) { Sv[j] = Svec[j * 16 + l15]; Bv[j] = bias2[j * 16 + l15]; }
#pragma unroll
  for (int i = 0; i < 2; ++i) {
#pragma unroll
    for (int r = 0; r < 4; ++r) {
      int a_local = wv * 32 + i * 16 + q * 4 + r;
      float2 ms = muRow[a_local];
      float mv = mask[(size_t)(a0 + a_local) * N_RES + b];
#pragma unroll
      for (int j = 0; j < 4; ++j) {
        float val = (ms.y * (acc[i][j][r] - ms.x * Sv[j]) + Bv[j]) * mv;
        outbuf[(j * 16 + l15) * 136 + a_local] = (bf16)val;
      }
    }
  }
  __syncthreads();

  // ---- D: coalesced write to leftT/rightT ----
  {
    int o = t >> 2, part = t & 3;
    bf16* dst = (o < 32) ? (leftT + (size_t)(b * 32 + o) * 512)
                         : (rightT + (size_t)(b * 32 + (o - 32)) * 512);
#pragma unroll
    for (int v = 0; v < 4; ++v) {
      int asub = part * 32 + v * 8;
      bf16x8 val = *(bf16x8*)&outbuf[o * 136 + asub];
      *(bf16x8*)(dst + a0 + asub) = val;
    }
  }
}

// ---------------- main kernel: 256x256 tile, 32-phase pipeline ----------------
// R1 skeleton (measured best) + stage-in-MFMA-window: per phase {ds_reads; counted vmcnt;
// barrier; STAGE issue (DMA lands while DS read pipe idles under MFMA); setprio; 8 MFMA;
// setprio; barrier}. A and B staged via global_load_lds into 4 rotating 16KB LDS blocks
// per matrix ([dbuf parity][k-half], [256 rows][32 k], XOR swizzle applied on the GLOBAL
// source so LDS dest stays linear). Counted vmcnt: steady 6 (3 units in flight), tail
// 6->4->0 — never a mid-loop drain.
__launch_bounds__(512, 2)
__global__ void outer_kernel(const bf16* __restrict__ leftT, const bf16* __restrict__ rightT,
                             const bf16* __restrict__ WtEp, const float* __restrict__ output_b,
                             const float* __restrict__ recip, float* __restrict__ out) {
  __shared__ __align__(16) union {
    bf16 AB[8 * 8192];       // 131072 B : [dbuf][A|B][khalf][256*32] swizzled bf16
    bf16 Aep[64 * 1156];     // 147968 B : inter tile, [pair][e*36 + c]
    float P[4 * 64 * 2 * 64];// 131072 B : epilogue partials [kq][pair][fh][fl]
  } sm;

  const int t_ = threadIdx.x;
  const int sq = blockIdx.x >> 4, wi = blockIdx.x & 15;
  const int m0 = ((sq % 12) * 4 + (wi & 3)) * 256;
  const int n0 = ((sq / 12) * 4 + (wi >> 2)) * 256;

  const int wv = t_ >> 6, lane = t_ & 63;
  const int q = lane >> 4, l15 = lane & 15;
  const int l31 = lane & 31, h = lane >> 5;
  const int wm = (wv & 1) * 128, wn = (wv >> 1) * 64;

  // staging constants: wave writes 2x1KB linear LDS; source k-chunk pre-swizzled so a
  // read of LDS[row][kc ^ ((row>>1)&3)] returns logical [row][kc]
  const int stR  = wv * 32 + (lane >> 2);                  // row, + _j*16
  const int stKC = ((lane & 3) ^ ((lane >> 3) & 3)) * 8;   // source k-chunk (elems)
  const int rsw  = (l31 >> 1) & 3;                         // read-side XOR term

  const bf16* gA = leftT  + (size_t)m0 * 512;
  const bf16* gB = rightT + (size_t)n0 * 512;

#define BLK(d, mat, hf) ((((d) * 2 + (mat)) * 2 + (hf)) * 8192)
#define STAGE(mat, T, hf) do {                                                              \
    const bf16* _g = (mat) ? gB : gA;                                                       \
    bf16* _l = sm.AB + BLK((T) & 1, mat, hf);                                               \
    _Pragma("unroll")                                                                       \
    for (int _j = 0; _j < 2; ++_j) {                                                        \
      const bf16* _s = _g + (size_t)(stR + _j * 16) * 512 + (T) * 64 + (hf) * 32 + stKC;    \
      __builtin_amdgcn_global_load_lds(                                                     \
          (const __attribute__((address_space(1))) void*)_s,                                \
          (__attribute__((address_space(3))) void*)(_l + (wv * 2 + _j) * 512), 16, 0, 0);   \
    }                                                                                       \
  } while (0)

  f32x16 acc[4][2] = {};

  // prologue: khalf(0,0), khalf(0,1), khalf(1,0) for both matrices (12 vmem instrs/wave);
  // counted wait: khalf(0,0) landed, the rest may stay in flight
  STAGE(0, 0, 0); STAGE(1, 0, 0);
  STAGE(0, 0, 1); STAGE(1, 0, 1);
  STAGE(0, 1, 0); STAGE(1, 1, 0);
  wait_vm<8>();
  __builtin_amdgcn_s_barrier();

#pragma unroll
  for (int t = 0; t < 8; ++t) {
#pragma unroll
    for (int s = 0; s < 4; ++s) {
      // register fragments for k16-step s (block resident: guarded by the counted vmcnt
      // of an earlier phase + two barriers)
      const bf16* Ab = sm.AB + BLK(t & 1, 0, s >> 1);
      const bf16* Bb = sm.AB + BLK(t & 1, 1, s >> 1);
      const int coff = (((s & 1) * 2 + h) ^ rsw) * 8;
      bf16x8 af[4], b0, b1;
#pragma unroll
      for (int i = 0; i < 4; ++i)
        af[i] = *(const bf16x8*)&Ab[(wm + i * 32 + l31) * 32 + coff];
      b0 = *(const bf16x8*)&Bb[(wn + l31) * 32 + coff];
      b1 = *(const bf16x8*)&Bb[(wn + 32 + l31) * 32 + coff];

      // counted vmcnt guarding the blocks consumed from the NEXT phase onward.
      // With stages issued inside MFMA windows, younger-than-target = 3 units = 6 instrs
      // steady; tail tightens 6 -> 4 -> 0.
      if (s == 1) { if (t < 7) wait_vm<6>(); else wait_vm<0>(); }
      if (s == 3) { if (t < 6) wait_vm<6>(); else if (t == 6) wait_vm<4>(); }

      __builtin_amdgcn_s_barrier();

      // stage issue INSIDE the MFMA window: DMA LDS-writes land while the DS read pipe
      // is idle (reads for next phase not yet issued) -> no read/write bank collisions.
      // P(t,0)->A(t+1,1); P(t,1)->B(t+1,1); P(t,2)->A(t+2,0); P(t,3)->B(t+2,0).
      if (s == 0) { if (t < 7) STAGE(0, t + 1, 1); }
      if (s == 1) { if (t < 7) STAGE(1, t + 1, 1); }
      if (s == 2) { if (t < 6) STAGE(0, t + 2, 0); }
      if (s == 3) { if (t < 6) STAGE(1, t + 2, 0); }

      __builtin_amdgcn_s_setprio(1);
#pragma unroll
      for (int i = 0; i < 4; ++i) {
        acc[i][0] = __builtin_amdgcn_mfma_f32_32x32x16_bf16(af[i], b0, acc[i][0], 0, 0, 0);
        acc[i][1] = __builtin_amdgcn_mfma_f32_32x32x16_bf16(af[i], b1, acc[i][1], 0, 0, 0);
      }
      __builtin_amdgcn_s_setprio(0);
      __builtin_amdgcn_s_barrier();   // readers done before next phase's stage overwrites
    }
  }
  __syncthreads();   // LDS union repurposed below (all DMA landed: t==7 issues no stages)

  // scatter inter tile -> Aep[pair][e*36 + c], b64-packed (4 consecutive c per reg-group)
#pragma unroll
  for (int i = 0; i < 4; ++i) {
#pragma unroll
    for (int j = 0; j < 2; ++j) {
      int pair = ((wv & 1) * 4 + i) * 8 + (wv >> 1) * 2 + j;
      int base = pair * 1156 + l31 * 36;   // e = l31
#pragma unroll
      for (int g = 0; g < 4; ++g) {
        bf16x4 v;
        v[0] = (bf16)acc[i][j][4 * g + 0];
        v[1] = (bf16)acc[i][j][4 * g + 1];
        v[2] = (bf16)acc[i][j][4 * g + 2];
        v[3] = (bf16)acc[i][j][4 * g + 3];
        *(bf16x4*)&sm.Aep[base + 8 * g + 4 * h] = v;   // c = 8g+4h+{0..3}
      }
    }
  }
  __syncthreads();

  // epilogue: each wave: k-slice 256 (kq), f-slice 64 (fh), all 64 pairs. W read once/block.
  const int kq = wv & 3, fh = wv >> 2;
  f32x4 eacc[4][4] = {};   // [mt][j]
#pragma unroll
  for (int si = 0; si < 8; ++si) {
    int e = kq * 8 + si;
    bf16x8 wf[4];
#pragma unroll
    for (int j = 0; j < 4; ++j)
      wf[j] = *(const bf16x8*)&WtEp[(size_t)(fh * 64 + j * 16 + l15) * 1024 + e * 32 + q * 8];
    bf16x8 af[4];
#pragma unroll
    for (int mt = 0; mt < 4; ++mt)
      af[mt] = ld8(&sm.Aep[(mt * 16 + l15) * 1156 + e * 36 + q * 8]);
#pragma unroll
    for (int mt = 0; mt < 4; ++mt)
#pragma unroll
      for (int j = 0; j < 4; ++j)
        eacc[mt][j] = __builtin_amdgcn_mfma_f32_16x16x32_bf16(af[mt], wf[j], eacc[mt][j], 0, 0, 0);
  }
  __syncthreads();

  // write partials P[kq][pair][fh][fl]
#pragma unroll
  for (int mt = 0; mt < 4; ++mt)
#pragma unroll
    for (int j = 0; j < 4; ++j)
#pragma unroll
      for (int r = 0; r < 4; ++r) {
        int pair = mt * 16 + q * 4 + r;
        int fl = j * 16 + l15;
        sm.P[((kq * 64 + pair) * 2 + fh) * 64 + fl] = eacc[mt][j][r];
      }
  __syncthreads();

  // reduce over kq, add bias, scale by recip, write out
#pragma unroll
  for (int gg = 0; gg < 4; ++gg) {
    int g = t_ + 512 * gg;          // [0, 2048)
    int pair = g >> 5, f4 = g & 31;
    int f = f4 * 4, fh2 = f >> 6, fl = f & 63;
    f32x4 s = {};
#pragma unroll
    for (int k2 = 0; k2 < 4; ++k2)
      s += *(f32x4*)&sm.P[((k2 * 64 + pair) * 2 + fh2) * 64 + fl];
    int b = (m0 >> 5) + (pair >> 3);
    int d = (n0 >> 5) + (pair & 7);
    float rc = recip[b * N_RES + d];
    float4 ob = *(const float4*)(output_b + f);
    f32x4 o;
    o[0] = (s[0] + ob.x) * rc; o[1] = (s[1] + ob.y) * rc;
    o[2] = (s[2] + ob.z) * rc; o[3] = (s[3] + ob.w) * rc;
    *(f32x4*)(out + ((size_t)b * N_RES + d) * 128 + f) = o;
  }
}

extern "C" void kernel_launch(void* const* d_in, const int* in_sizes, int n_in,
                              void* d_out, int out_size, void* d_ws, size_t ws_size,
                              hipStream_t stream) {
  const float* act       = (const float*)d_in[0];
  const float* mask      = (const float*)d_in[1];
  const float* ln_scale  = (const float*)d_in[2];
  const float* ln_offset = (const float*)d_in[3];
  const float* left_w    = (const float*)d_in[4];
  const float* left_b    = (const float*)d_in[5];
  const float* right_w   = (const float*)d_in[6];
  const float* right_b   = (const float*)d_in[7];
  const float* output_w  = (const float*)d_in[8];
  const float* output_b  = (const float*)d_in[9];
  float* out = (float*)d_out;

  char* ws = (char*)d_ws;
  bf16* leftT   = (bf16*)(ws);
  bf16* rightT  = (bf16*)(ws + 12582912);
  bf16* WtEp    = (bf16*)(ws + 25165824);
  bf16* projW2  = (bf16*)(ws + 25427968);
  float* Svec   = (float*)(ws + 25460736);
  float* bias2  = (float*)(ws + 25460992);
  float* recip  = (float*)(ws + 25461248);

  hipLaunchKernelGGL(aux_kernel, dim3(1153), dim3(256), 0, stream,
                     mask, left_w, right_w, output_w, ln_scale, ln_offset,
                     left_b, right_b, projW2, WtEp, Svec, bias2, recip);
  hipLaunchKernelGGL(ln_project_kernel, dim3(4, 384), dim3(256), 0, stream,
                     act, mask, projW2, Svec, bias2, leftT, rightT);
  hipLaunchKernelGGL(outer_kernel, dim3(2304), dim3(512), 0, stream,
                     leftT, rightT, WtEp, output_b, recip, out);
}

// Round 4
// 565.952 us; speedup vs baseline: 1.0731x; 1.0227x over previous
//
#include <hip/hip_runtime.h>

#define N_SEQ 512
#define N_RES 384
#define C_M   256

typedef __bf16 bf16;
typedef __bf16 bf16x4 __attribute__((ext_vector_type(4)));
typedef __bf16 bf16x8 __attribute__((ext_vector_type(8)));
typedef float  f32x4  __attribute__((ext_vector_type(4)));
typedef float  f32x16 __attribute__((ext_vector_type(16)));

static __device__ __forceinline__ bf16x8 ld8(const bf16* p) {
  bf16x4 lo = *(const bf16x4*)p;
  bf16x4 hi = *(const bf16x4*)(p + 4);
  bf16x8 r;
  r[0] = lo[0]; r[1] = lo[1]; r[2] = lo[2]; r[3] = lo[3];
  r[4] = hi[0]; r[5] = hi[1]; r[6] = hi[2]; r[7] = hi[3];
  return r;
}

// s_waitcnt vmcnt(N) only (lgkmcnt/expcnt = no-wait)
template <int N> __device__ __forceinline__ void wait_vm() {
  __builtin_amdgcn_s_waitcnt((N & 15) | ((N >> 4) << 14) | (7 << 4) | (15 << 8));
}

// Workspace layout (bytes):
//   leftT  [12288][512] bf16 @ 0          (m=b*32+c, k=a)
//   rightT [12288][512] bf16 @ 12582912   (n=d*32+e, k=a)
//   WtEp   [128][1024]  bf16 @ 25165824   (f, k=e*32+c)  e-major!
//   projW2 [64][256]    bf16 @ 25427968   (o, m)  = g[m]*w[m][o]
//   Svec   [64] f32     @ 25460736        column sums of projW2
//   bias2  [64] f32     @ 25460992        bias + o@w
//   recip  [384*384] f32 @ 25461248

// ---------------- aux: norm + weight prep, one launch ----------------
__global__ void aux_kernel(const float* __restrict__ mask,
                           const float* __restrict__ lw, const float* __restrict__ rw,
                           const float* __restrict__ ow,
                           const float* __restrict__ ln_scale, const float* __restrict__ ln_offset,
                           const float* __restrict__ left_b, const float* __restrict__ right_b,
                           bf16* __restrict__ projW2, bf16* __restrict__ WtEp,
                           float* __restrict__ Svec, float* __restrict__ bias2,
                           float* __restrict__ recip) {
  int blk = blockIdx.x, t = threadIdx.x;
  if (blk < 576) {
    int bx = blk % 24, by = blk / 24;
    int b = bx * 16 + (t & 15), d = by * 16 + (t >> 4);
    float s = 0.f;
#pragma unroll 8
    for (int a = 0; a < N_SEQ; ++a)
      s += mask[a * N_RES + b] * mask[a * N_RES + d];
    recip[b * N_RES + d] = 1.0f / (1e-3f + s);
  } else if (blk < 1088) {
    int i2 = (blk - 576) * 256 + t;          // [0, 131072)
    int f = i2 >> 10, k = i2 & 1023, e = k >> 5, c = k & 31;
    WtEp[i2] = (bf16)ow[(c * 32 + e) * 128 + f];   // WtEp[f][e*32+c]
  } else if (blk < 1152) {
    int idx = (blk - 1088) * 256 + t;        // [0, 16384)
    int o = idx >> 8, m = idx & 255;
    float w = (o < 32) ? lw[m * 32 + o] : rw[m * 32 + (o - 32)];
    projW2[idx] = (bf16)(ln_scale[m] * w);
  } else {
    if (t < 64) {
      int o = t;
      float s = 0.f, b2 = (o < 32) ? left_b[o] : right_b[o - 32];
      for (int m = 0; m < 256; ++m) {
        float w = (o < 32) ? lw[m * 32 + o] : rw[m * 32 + (o - 32)];
        s += (float)(bf16)(ln_scale[m] * w);   // match MFMA's bf16 W' exactly
        b2 += ln_offset[m] * w;
      }
      Svec[o] = s; bias2[o] = b2;
    }
  }
}

// ---------------- LN + projection: stats via LDS pass, mean-correction post-GEMM ----------------
// block: 128 a-rows, fixed b. grid (4, 384).
__launch_bounds__(256)
__global__ void ln_project_kernel(const float* __restrict__ act, const float* __restrict__ mask,
                                  const bf16* __restrict__ projW2,
                                  const float* __restrict__ Svec, const float* __restrict__ bias2,
                                  bf16* __restrict__ leftT, bf16* __restrict__ rightT) {
  __shared__ __align__(16) bf16 At[128 * 264];   // raw bf16 x, [128][256+8]
  __shared__ float2 muRow[128];
  bf16* outbuf = At;                             // aliased after GEMM: [64 o][136 a]

  const int t = threadIdx.x;
  const int b = blockIdx.y;
  const int a0 = blockIdx.x * 128;
  const int wv = t >> 6, lane = t & 63;
  const int q = lane >> 4, l15 = lane & 15;

  // ---- A: coalesced 1KB row loads, store raw bf16 ----
#pragma unroll 4
  for (int it = 0; it < 32; ++it) {
    const int row = it * 4 + wv;
    float4 v = *(const float4*)(act + ((size_t)(a0 + row) * N_RES + b) * C_M + lane * 4);
    bf16x4 r;
    r[0] = (bf16)v.x; r[1] = (bf16)v.y; r[2] = (bf16)v.z; r[3] = (bf16)v.w;
    *(bf16x4*)&At[row * 264 + lane * 4] = r;
  }
  __syncthreads();

  // ---- A2: per-half-row stats from LDS (no butterfly storm) ----
  {
    int row = t >> 1, half = t & 1;
    const bf16* base = At + row * 264 + half * 128;
    float s1 = 0.f, s2 = 0.f;
#pragma unroll
    for (int i = 0; i < 16; ++i) {
      int ch = ((i + row) & 15) * 8;             // rotation breaks bank collisions
      bf16x8 v = *(const bf16x8*)(base + ch);
#pragma unroll
      for (int u = 0; u < 8; ++u) { float x = (float)v[u]; s1 += x; s2 += x * x; }
    }
    s1 += __shfl_xor(s1, 1);
    s2 += __shfl_xor(s2, 1);
    if (half == 0) {
      float mean = s1 * (1.f / 256.f);
      float var  = s2 * (1.f / 256.f) - mean * mean;
      muRow[row] = make_float2(mean, rsqrtf(var + 1e-5f));
    }
  }

  // ---- B: GEMM raw x @ W'  (M=128, N=64, K=256) ----
  f32x4 acc[2][4] = {};
#pragma unroll
  for (int s = 0; s < 8; ++s) {
    bf16x8 af[2], bfr[4];
#pragma unroll
    for (int i = 0; i < 2; ++i)
      af[i] = *(bf16x8*)&At[(wv * 32 + i * 16 + l15) * 264 + s * 32 + q * 8];
#pragma unroll
    for (int j = 0; j < 4; ++j)
      bfr[j] = *(const bf16x8*)&projW2[(j * 16 + l15) * 256 + s * 32 + q * 8];
#pragma unroll
    for (int i = 0; i < 2; ++i)
#pragma unroll
      for (int j = 0; j < 4; ++j)
        acc[i][j] = __builtin_amdgcn_mfma_f32_16x16x32_bf16(af[i], bfr[j], acc[i][j], 0, 0, 0);
  }
  __syncthreads();

  // ---- C: z = rstd*(P - mu*S) + bias2, then *mask ----
  float Sv[4], Bv[4];
#pragma unroll
  for (int j = 0; j < 4; ++j) { Sv[j] = Svec[j * 16 + l15]; Bv[j] = bias2[j * 16 + l15]; }
#pragma unroll
  for (int i = 0; i < 2; ++i) {
#pragma unroll
    for (int r = 0; r < 4; ++r) {
      int a_local = wv * 32 + i * 16 + q * 4 + r;
      float2 ms = muRow[a_local];
      float mv = mask[(size_t)(a0 + a_local) * N_RES + b];
#pragma unroll
      for (int j = 0; j < 4; ++j) {
        float val = (ms.y * (acc[i][j][r] - ms.x * Sv[j]) + Bv[j]) * mv;
        outbuf[(j * 16 + l15) * 136 + a_local] = (bf16)val;
      }
    }
  }
  __syncthreads();

  // ---- D: coalesced write to leftT/rightT ----
  {
    int o = t >> 2, part = t & 3;
    bf16* dst = (o < 32) ? (leftT + (size_t)(b * 32 + o) * 512)
                         : (rightT + (size_t)(b * 32 + (o - 32)) * 512);
#pragma unroll
    for (int v = 0; v < 4; ++v) {
      int asub = part * 32 + v * 8;
      bf16x8 val = *(bf16x8*)&outbuf[o * 136 + asub];
      *(bf16x8*)(dst + a0 + asub) = val;
    }
  }
}

// ---------------- main kernel: 256x256 tile, 32-phase SINGLE-barrier pipeline ----------------
// Per phase: {ds_reads; counted vmcnt (odd phases only); ONE barrier; stage issue; setprio;
// 8 MFMA; setprio}. No trailing barrier: waves drift up to one phase, overlapping one
// wave-group's DS reads under another's MFMA. Overwrite hazard covered by the single
// barrier: stage_p targets the slot last read at reads_{p-1}, which completed before its
// owner's MFMA_{p-1} (compiler lgkmcnt), which precedes arrival at B_p.
// Counted vmcnt only at odd phases (new slots are consumed only at even phases):
// vm(8) steady (slot q-5 landed, 4 units in flight), tail vm(4)@27, vm(0)@29.
__launch_bounds__(512, 2)
__global__ void outer_kernel(const bf16* __restrict__ leftT, const bf16* __restrict__ rightT,
                             const bf16* __restrict__ WtEp, const float* __restrict__ output_b,
                             const float* __restrict__ recip, float* __restrict__ out) {
  __shared__ __align__(16) union {
    bf16 AB[8 * 8192];       // 131072 B : [dbuf][A|B][khalf][256*32] swizzled bf16
    bf16 Aep[64 * 1156];     // 147968 B : inter tile, [pair][e*36 + c]
    float P[4 * 64 * 2 * 64];// 131072 B : epilogue partials [kq][pair][fh][fl]
  } sm;

  const int t_ = threadIdx.x;
  const int sq = blockIdx.x >> 4, wi = blockIdx.x & 15;
  const int m0 = ((sq % 12) * 4 + (wi & 3)) * 256;
  const int n0 = ((sq / 12) * 4 + (wi >> 2)) * 256;

  const int wv = t_ >> 6, lane = t_ & 63;
  const int q = lane >> 4, l15 = lane & 15;
  const int l31 = lane & 31, h = lane >> 5;
  const int wm = (wv & 1) * 128, wn = (wv >> 1) * 64;

  // staging constants: wave writes 2x1KB linear LDS; source k-chunk pre-swizzled so a
  // read of LDS[row][kc ^ ((row>>1)&3)] returns logical [row][kc]
  const int stR  = wv * 32 + (lane >> 2);                  // row, + _j*16
  const int stKC = ((lane & 3) ^ ((lane >> 3) & 3)) * 8;   // source k-chunk (elems)
  const int rsw  = (l31 >> 1) & 3;                         // read-side XOR term

  const bf16* gA = leftT  + (size_t)m0 * 512;
  const bf16* gB = rightT + (size_t)n0 * 512;

#define BLK(d, mat, hf) ((((d) * 2 + (mat)) * 2 + (hf)) * 8192)
#define STAGE(mat, T, hf) do {                                                              \
    const bf16* _g = (mat) ? gB : gA;                                                       \
    bf16* _l = sm.AB + BLK((T) & 1, mat, hf);                                               \
    _Pragma("unroll")                                                                       \
    for (int _j = 0; _j < 2; ++_j) {                                                        \
      const bf16* _s = _g + (size_t)(stR + _j * 16) * 512 + (T) * 64 + (hf) * 32 + stKC;    \
      __builtin_amdgcn_global_load_lds(                                                     \
          (const __attribute__((address_space(1))) void*)_s,                                \
          (__attribute__((address_space(3))) void*)(_l + (wv * 2 + _j) * 512), 16, 0, 0);   \
    }                                                                                       \
  } while (0)

  f32x16 acc[4][2] = {};

  // prologue: khalf(0,0), khalf(0,1), khalf(1,0) for both matrices (12 vmem instrs/wave);
  // counted wait: khalf(0,0) landed, the rest may stay in flight
  STAGE(0, 0, 0); STAGE(1, 0, 0);
  STAGE(0, 0, 1); STAGE(1, 0, 1);
  STAGE(0, 1, 0); STAGE(1, 1, 0);
  wait_vm<8>();
  __builtin_amdgcn_s_barrier();

#pragma unroll
  for (int t = 0; t < 8; ++t) {
#pragma unroll
    for (int s = 0; s < 4; ++s) {
      // ---- reads (phase start): guarded by the PREVIOUS odd phase's vmcnt + barrier ----
      const bf16* Ab = sm.AB + BLK(t & 1, 0, s >> 1);
      const bf16* Bb = sm.AB + BLK(t & 1, 1, s >> 1);
      const int coff = (((s & 1) * 2 + h) ^ rsw) * 8;
      bf16x8 af[4], b0, b1;
#pragma unroll
      for (int i = 0; i < 4; ++i)
        af[i] = *(const bf16x8*)&Ab[(wm + i * 32 + l31) * 32 + coff];
      b0 = *(const bf16x8*)&Bb[(wn + l31) * 32 + coff];
      b1 = *(const bf16x8*)&Bb[(wn + 32 + l31) * 32 + coff];

      // ---- counted vmcnt at ODD phases only (new slots consumed at even phases):
      // steady vm(8): stage for next phase-pair landed, 4 units in flight.
      // Tail: p==27 -> vm(4), p==29 -> vm(0). Even phases re-read same slots: no wait.
      {
        const int p = 4 * t + s;
        if (p & 1) {
          if (p <= 25)      wait_vm<8>();
          else if (p == 27) wait_vm<4>();
          else if (p == 29) wait_vm<0>();
          // p == 31: nothing outstanding
        }
      }

      __builtin_amdgcn_s_barrier();   // the ONE barrier per phase

      // ---- stage issue after the barrier: target slot's old readers finished at
      // reads_{p-1}, completed before their MFMA_{p-1} which precedes B_p. ----
      if (s == 0) { if (t < 7) STAGE(0, t + 1, 1); }
      if (s == 1) { if (t < 7) STAGE(1, t + 1, 1); }
      if (s == 2) { if (t < 6) STAGE(0, t + 2, 0); }
      if (s == 3) { if (t < 6) STAGE(1, t + 2, 0); }

      __builtin_amdgcn_s_setprio(1);
#pragma unroll
      for (int i = 0; i < 4; ++i) {
        acc[i][0] = __builtin_amdgcn_mfma_f32_32x32x16_bf16(af[i], b0, acc[i][0], 0, 0, 0);
        acc[i][1] = __builtin_amdgcn_mfma_f32_32x32x16_bf16(af[i], b1, acc[i][1], 0, 0, 0);
      }
      __builtin_amdgcn_s_setprio(0);
      // no trailing barrier: next phase's leading barrier provides the separation
    }
  }
  __syncthreads();   // LDS union repurposed below (all DMA landed via p==29 vm(0))

  // scatter inter tile -> Aep[pair][e*36 + c], b64-packed (4 consecutive c per reg-group)
#pragma unroll
  for (int i = 0; i < 4; ++i) {
#pragma unroll
    for (int j = 0; j < 2; ++j) {
      int pair = ((wv & 1) * 4 + i) * 8 + (wv >> 1) * 2 + j;
      int base = pair * 1156 + l31 * 36;   // e = l31
#pragma unroll
      for (int g = 0; g < 4; ++g) {
        bf16x4 v;
        v[0] = (bf16)acc[i][j][4 * g + 0];
        v[1] = (bf16)acc[i][j][4 * g + 1];
        v[2] = (bf16)acc[i][j][4 * g + 2];
        v[3] = (bf16)acc[i][j][4 * g + 3];
        *(bf16x4*)&sm.Aep[base + 8 * g + 4 * h] = v;   // c = 8g+4h+{0..3}
      }
    }
  }
  __syncthreads();

  // epilogue: each wave: k-slice 256 (kq), f-slice 64 (fh), all 64 pairs. W read once/block.
  const int kq = wv & 3, fh = wv >> 2;
  f32x4 eacc[4][4] = {};   // [mt][j]
#pragma unroll
  for (int si = 0; si < 8; ++si) {
    int e = kq * 8 + si;
    bf16x8 wf[4];
#pragma unroll
    for (int j = 0; j < 4; ++j)
      wf[j] = *(const bf16x8*)&WtEp[(size_t)(fh * 64 + j * 16 + l15) * 1024 + e * 32 + q * 8];
    bf16x8 af[4];
#pragma unroll
    for (int mt = 0; mt < 4; ++mt)
      af[mt] = ld8(&sm.Aep[(mt * 16 + l15) * 1156 + e * 36 + q * 8]);
#pragma unroll
    for (int mt = 0; mt < 4; ++mt)
#pragma unroll
      for (int j = 0; j < 4; ++j)
        eacc[mt][j] = __builtin_amdgcn_mfma_f32_16x16x32_bf16(af[mt], wf[j], eacc[mt][j], 0, 0, 0);
  }
  __syncthreads();

  // write partials P[kq][pair][fh][fl]
#pragma unroll
  for (int mt = 0; mt < 4; ++mt)
#pragma unroll
    for (int j = 0; j < 4; ++j)
#pragma unroll
      for (int r = 0; r < 4; ++r) {
        int pair = mt * 16 + q * 4 + r;
        int fl = j * 16 + l15;
        sm.P[((kq * 64 + pair) * 2 + fh) * 64 + fl] = eacc[mt][j][r];
      }
  __syncthreads();

  // reduce over kq, add bias, scale by recip, write out
#pragma unroll
  for (int gg = 0; gg < 4; ++gg) {
    int g = t_ + 512 * gg;          // [0, 2048)
    int pair = g >> 5, f4 = g & 31;
    int f = f4 * 4, fh2 = f >> 6, fl = f & 63;
    f32x4 s = {};
#pragma unroll
    for (int k2 = 0; k2 < 4; ++k2)
      s += *(f32x4*)&sm.P[((k2 * 64 + pair) * 2 + fh2) * 64 + fl];
    int b = (m0 >> 5) + (pair >> 3);
    int d = (n0 >> 5) + (pair & 7);
    float rc = recip[b * N_RES + d];
    float4 ob = *(const float4*)(output_b + f);
    f32x4 o;
    o[0] = (s[0] + ob.x) * rc; o[1] = (s[1] + ob.y) * rc;
    o[2] = (s[2] + ob.z) * rc; o[3] = (s[3] + ob.w) * rc;
    *(f32x4*)(out + ((size_t)b * N_RES + d) * 128 + f) = o;
  }
}

extern "C" void kernel_launch(void* const* d_in, const int* in_sizes, int n_in,
                              void* d_out, int out_size, void* d_ws, size_t ws_size,
                              hipStream_t stream) {
  const float* act       = (const float*)d_in[0];
  const float* mask      = (const float*)d_in[1];
  const float* ln_scale  = (const float*)d_in[2];
  const float* ln_offset = (const float*)d_in[3];
  const float* left_w    = (const float*)d_in[4];
  const float* left_b    = (const float*)d_in[5];
  const float* right_w   = (const float*)d_in[6];
  const float* right_b   = (const float*)d_in[7];
  const float* output_w  = (const float*)d_in[8];
  const float* output_b  = (const float*)d_in[9];
  float* out = (float*)d_out;

  char* ws = (char*)d_ws;
  bf16* leftT   = (bf16*)(ws);
  bf16* rightT  = (bf16*)(ws + 12582912);
  bf16* WtEp    = (bf16*)(ws + 25165824);
  bf16* projW2  = (bf16*)(ws + 25427968);
  float* Svec   = (float*)(ws + 25460736);
  float* bias2  = (float*)(ws + 25460992);
  float* recip  = (float*)(ws + 25461248);

  hipLaunchKernelGGL(aux_kernel, dim3(1153), dim3(256), 0, stream,
                     mask, left_w, right_w, output_w, ln_scale, ln_offset,
                     left_b, right_b, projW2, WtEp, Svec, bias2, recip);
  hipLaunchKernelGGL(ln_project_kernel, dim3(4, 384), dim3(256), 0, stream,
                     act, mask, projW2, Svec, bias2, leftT, rightT);
  hipLaunchKernelGGL(outer_kernel, dim3(2304), dim3(512), 0, stream,
                     leftT, rightT, WtEp, output_b, recip, out);
}